// Round 10
// baseline (70.828 us; speedup 1.0000x reference)
//
#include <hip/hip_runtime.h>
#include <math.h>

#define C      128
#define CAPLG  12
#define CAP    (1 << CAPLG)      // bucket capacity per class (max count ~2300 << 4096)
#define SPLIT  16                // blocks per class in main pass
#define SPB    1024              // samples per scatter block
#define REDN   (2*C*C + 2*C)     // sp[CC], sln[CC], cnt[C], pos[C]
#define PBS    260               // per-block partial stride: sp[128] sln[128] pos pad
#define LN2F   0.69314718056f

__device__ __forceinline__ float fast_rcp(float x) { return __builtin_amdgcn_rcpf(x); }

// ---------------------------------------------------------------------------
// Bucketed counting-sort scatter (verbatim round-5 champion).
__global__ __launch_bounds__(256)
void scatter_kernel(const int* __restrict__ tgt, int* __restrict__ cursor,
                    int* __restrict__ perm, int B) {
    __shared__ int lcur[C];
    __shared__ int sbase[C];
    if (threadIdx.x < C) lcur[threadIdx.x] = 0;
    __syncthreads();
    const int base = blockIdx.x * SPB;
    int myt[SPB / 256], myr[SPB / 256];
#pragma unroll
    for (int j = 0; j < SPB / 256; ++j) {
        int i = base + j * 256 + threadIdx.x;
        if (i < B) { myt[j] = tgt[i]; myr[j] = atomicAdd(&lcur[myt[j]], 1); }
        else myt[j] = -1;
    }
    __syncthreads();
    if (threadIdx.x < C) sbase[threadIdx.x] = atomicAdd(&cursor[threadIdx.x], lcur[threadIdx.x]);
    __syncthreads();
#pragma unroll
    for (int j = 0; j < SPB / 256; ++j)
        if (myt[j] >= 0)
            perm[(myt[j] << CAPLG) + sbase[myt[j]] + myr[j]] = base + j * 256 + threadIdx.x;
}

// ---------------------------------------------------------------------------
// Main pass (verbatim round-5 champion): float2/lane, depth-2 prefetch,
// perm tile broadcast via shfl, register accumulate, LDS cross-wave reduce,
// row-major block-local partial write.
__global__ __launch_bounds__(256)
void main_kernel(const float* __restrict__ x, const int* __restrict__ perm,
                 const int* __restrict__ cursor, float* __restrict__ partial) {
    const int k = blockIdx.x / SPLIT;
    const int p = blockIdx.x % SPLIT;
    const int n = min(cursor[k], CAP);
    const int chunk = (n + SPLIT - 1) / SPLIT;
    const int s0 = min(p * chunk, n);
    const int s1 = min(s0 + chunk, n);

    const int tid  = threadIdx.x;
    const int wave = tid >> 6;
    const int lane = tid & 63;
    const int half = lane >> 5;          // 0 => row A, 1 => row B
    const int l5   = lane & 31;
    const int c0   = l5 << 2;            // this lane's first of 4 columns
    const bool poslane = (l5 == (k >> 2));
    const int  ksub = k & 3;

    const int wlen = (s1 - s0 + 3) >> 2; // per-wave contiguous sub-range
    const int ws0  = s0 + wave * wlen;
    const int ws1  = min(ws0 + wlen, s1);

    const int* bperm = perm + (k << CAPLG);

    float ap0=0,ap1=0,ap2=0,ap3=0;       // sum p
    float sx0=0,sx1=0,sx2=0,sx3=0;       // sum x
    float sl0=0,sl1=0,sl2=0,sl3=0;       // sum log2(1+exp(-x))
    float apos = 0.f;

    for (int tbase = ws0; tbase < ws1; tbase += 64) {
        const int tl = min(64, ws1 - tbase);
        const int pv = (lane < tl) ? bperm[tbase + lane] : 0;  // one load / 64 samples
        const int h  = (tl + 1) >> 1;
        int iA = __shfl(pv, 0);
        int iB = __shfl(pv, (h < tl) ? h : 0);
        float4 cur = *reinterpret_cast<const float4*>(
                         x + (size_t)(half ? iB : iA) * C + c0);
        for (int j = 0; j < h; ++j) {
            float4 nxt = cur;
            if (j + 1 < h) {   // prefetch next pair while computing current
                int nA = __shfl(pv, j + 1);
                int nB = __shfl(pv, (j + 1 + h < tl) ? j + 1 + h : j + 1);
                nxt = *reinterpret_cast<const float4*>(
                          x + (size_t)(half ? nB : nA) * C + c0);
            }
            const bool valid = (half == 0) || (j + h < tl);
            if (valid) {
                float e, u, lu0, lu1, lu2, lu3;
                e = __expf(-cur.x); u = 1.f + e; lu0 = __log2f(u);
                ap0 += fast_rcp(u); sx0 += cur.x; sl0 += lu0;
                e = __expf(-cur.y); u = 1.f + e; lu1 = __log2f(u);
                ap1 += fast_rcp(u); sx1 += cur.y; sl1 += lu1;
                e = __expf(-cur.z); u = 1.f + e; lu2 = __log2f(u);
                ap2 += fast_rcp(u); sx2 += cur.z; sl2 += lu2;
                e = __expf(-cur.w); u = 1.f + e; lu3 = __log2f(u);
                ap3 += fast_rcp(u); sx3 += cur.w; sl3 += lu3;
                if (poslane) {   // target-column log2(1+e) (k uniform -> uniform select)
                    float lsel = (ksub & 2) ? ((ksub & 1) ? lu3 : lu2)
                                            : ((ksub & 1) ? lu1 : lu0);
                    apos += lsel;
                }
            }
            cur = nxt;
        }
    }

    // ---- cross-wave/half LDS reduce (plain float4 writes, no atomics) ----
    __shared__ __align__(16) float sP[8][C];
    __shared__ __align__(16) float sX[8][C];
    __shared__ __align__(16) float sL[8][C];
    __shared__ float sPos[8];
    const int g = (wave << 1) | half;
    *reinterpret_cast<float4*>(&sP[g][c0]) = make_float4(ap0, ap1, ap2, ap3);
    *reinterpret_cast<float4*>(&sX[g][c0]) = make_float4(sx0, sx1, sx2, sx3);
    *reinterpret_cast<float4*>(&sL[g][c0]) = make_float4(sl0, sl1, sl2, sl3);
    if (poslane) sPos[g] = apos;
    __syncthreads();

    float* mine = partial + (size_t)blockIdx.x * PBS;
    if (tid < C) {                        // sum_probs col
        float s = 0.f;
#pragma unroll
        for (int g2 = 0; g2 < 8; ++g2) s += sP[g2][tid];
        mine[tid] = s;
    } else {                              // sum_logneg col: -sum(x) - ln2*sum(log2(1+e))
        const int t = tid - C;
        float sx = 0.f, sl = 0.f;
#pragma unroll
        for (int g2 = 0; g2 < 8; ++g2) { sx += sX[g2][t]; sl += sL[g2][t]; }
        mine[C + t] = -sx - LN2F * sl;
    }
    if (tid == 0) {
        float s = 0.f;
#pragma unroll
        for (int g2 = 0; g2 < 8; ++g2) s += sPos[g2];
        mine[256] = -LN2F * s;            // sum over samples of ln(p_target)
    }
}

// ---------------------------------------------------------------------------
// Sum the SPLIT partials of each class into red (verbatim round 5).
__global__ __launch_bounds__(256)
void reduce2_kernel(const float* __restrict__ partial, const int* __restrict__ cursor,
                    float* __restrict__ red) {
    const int k = blockIdx.x;
    const int t = threadIdx.x;
    float s = 0.f;
#pragma unroll
    for (int p = 0; p < SPLIT; ++p)
        s += partial[(size_t)(k * SPLIT + p) * PBS + t];
    if (t < C) red[k * C + t] = s;                 // sum_probs row k
    else       red[C * C + k * C + (t - C)] = s;   // sum_logneg row k
    if (t == 0) {
        float ps = 0.f;
#pragma unroll
        for (int p = 0; p < SPLIT; ++p)
            ps += partial[(size_t)(k * SPLIT + p) * PBS + 256];
        red[2 * C * C + C + k] = ps;               // pos[k]
        red[2 * C * C + k]     = (float)cursor[k]; // cnt[k]
    }
}

// ---------------------------------------------------------------------------
// Finalize stage 1 (verbatim round 5): one wave per column k.
__global__ __launch_bounds__(64)
void finalize_col_kernel(const float* __restrict__ red, float* __restrict__ colpart) {
    const float* sp  = red;                   // sum_probs  [C][C]
    const float* sln = red + C * C;           // sum_logneg [C][C]
    const float* cnt = red + 2 * C * C;       // [C]
    const float* pos = red + 2 * C * C + C;   // [C]

    const int k = blockIdx.x;
    const int l = threadIdx.x;
    const int j0 = l, j1 = l + 64;

    const float c0 = cnt[j0], c1 = cnt[j1];
    const bool  v0 = (j0 != k) && (c0 > 0.f);
    const bool  v1 = (j1 != k) && (c1 > 0.f);

    const float x0 = v0 ? sp[j0 * C + k] / c0 : -INFINITY;
    const float x1 = v1 ? sp[j1 * C + k] / c1 : -INFINITY;

    float m = fmaxf(x0, x1);
#pragma unroll
    for (int d = 1; d < 64; d <<= 1) m = fmaxf(m, __shfl_xor(m, d));

    float w0 = v0 ? __expf(x0 - m) : 0.f;
    float w1 = v1 ? __expf(x1 - m) : 0.f;
    float den = w0 + w1;
    float num = (v0 ? w0 * (sln[j0 * C + k] / c0) : 0.f)
              + (v1 ? w1 * (sln[j1 * C + k] / c1) : 0.f);
#pragma unroll
    for (int d = 1; d < 64; d <<= 1) { den += __shfl_xor(den, d); num += __shfl_xor(num, d); }

    if (l == 0) {
        float colneg = (den > 0.f) ? num / den : 0.f;
        float ck     = cnt[k];
        float pk     = (ck > 0.f) ? pos[k] / ck : 0.f;
        colpart[k]   = colneg + pk;
    }
}

// Finalize stage 2 (verbatim round 5): single wave sums the column partials.
__global__ __launch_bounds__(64)
void finalize_sum_kernel(const float* __restrict__ colpart, float* __restrict__ out) {
    const int l = threadIdx.x;
    float s = colpart[l] + colpart[l + 64];
#pragma unroll
    for (int d = 1; d < 64; d <<= 1) s += __shfl_xor(s, d);
    if (l == 0) out[0] = -s;
}

// ---------------------------------------------------------------------------
extern "C" void kernel_launch(void* const* d_in, const int* in_sizes, int n_in,
                              void* d_out, int out_size, void* d_ws, size_t ws_size,
                              hipStream_t stream) {
    const float* x   = (const float*)d_in[0];
    const int*   tgt = (const int*)d_in[1];
    const int B = in_sizes[1];

    int*   cursor   = (int*)d_ws;                          // C
    int*   perm     = cursor + C;                          // C*CAP
    float* partial  = (float*)(perm + C * CAP);            // C*SPLIT*PBS
    float* partial2 = partial + (size_t)(C * SPLIT) * PBS; // C*SPLIT*PBS (timing probe)
    float* red      = partial2 + (size_t)(C * SPLIT) * PBS;// REDN
    float* colpart  = red + REDN;                          // C

    hipMemsetAsync(cursor, 0, C * sizeof(int), stream);
    scatter_kernel<<<(B + SPB - 1) / SPB, 256, 0, stream>>>(tgt, cursor, perm, B);
    // timing probe: identical main launched twice; second result is unused.
    // dur_delta vs round-5 baseline (48.3 us) = T_main + one launch gap.
    main_kernel<<<C * SPLIT, 256, 0, stream>>>(x, perm, cursor, partial);
    main_kernel<<<C * SPLIT, 256, 0, stream>>>(x, perm, cursor, partial2);
    reduce2_kernel<<<C, 256, 0, stream>>>(partial, cursor, red);
    finalize_col_kernel<<<C, 64, 0, stream>>>(red, colpart);
    finalize_sum_kernel<<<1, 64, 0, stream>>>(colpart, (float*)d_out);
}

// Round 11
// 50.684 us; speedup vs baseline: 1.3975x; 1.3975x over previous
//
#include <hip/hip_runtime.h>
#include <math.h>

#define C      128
#define CAPLG  12
#define CAP    (1 << CAPLG)      // bucket capacity per class (max count ~2300 << 4096)
#define SPLIT  16                // blocks per class in main pass
#define SPB    1024              // samples per scatter block
#define PBS    260               // per-block partial stride: sp[128] sln[128] pos pad
#define LN2F   0.69314718056f

__device__ __forceinline__ float fast_rcp(float x) { return __builtin_amdgcn_rcpf(x); }

// ---------------------------------------------------------------------------
// Bucketed counting-sort scatter (verbatim round-5 champion).
__global__ __launch_bounds__(256)
void scatter_kernel(const int* __restrict__ tgt, int* __restrict__ cursor,
                    int* __restrict__ perm, int B) {
    __shared__ int lcur[C];
    __shared__ int sbase[C];
    if (threadIdx.x < C) lcur[threadIdx.x] = 0;
    __syncthreads();
    const int base = blockIdx.x * SPB;
    int myt[SPB / 256], myr[SPB / 256];
#pragma unroll
    for (int j = 0; j < SPB / 256; ++j) {
        int i = base + j * 256 + threadIdx.x;
        if (i < B) { myt[j] = tgt[i]; myr[j] = atomicAdd(&lcur[myt[j]], 1); }
        else myt[j] = -1;
    }
    __syncthreads();
    if (threadIdx.x < C) sbase[threadIdx.x] = atomicAdd(&cursor[threadIdx.x], lcur[threadIdx.x]);
    __syncthreads();
#pragma unroll
    for (int j = 0; j < SPB / 256; ++j)
        if (myt[j] >= 0)
            perm[(myt[j] << CAPLG) + sbase[myt[j]] + myr[j]] = base + j * 256 + threadIdx.x;
}

// ---------------------------------------------------------------------------
// Main pass (verbatim round-5 champion — measured at the transcendental
// roofline ~21 us; DO NOT TOUCH): float4/lane over 2 rows, depth-2 prefetch,
// perm tile broadcast via shfl, register accumulate, LDS cross-wave reduce,
// row-major block-local partial write.
__global__ __launch_bounds__(256)
void main_kernel(const float* __restrict__ x, const int* __restrict__ perm,
                 const int* __restrict__ cursor, float* __restrict__ partial) {
    const int k = blockIdx.x / SPLIT;
    const int p = blockIdx.x % SPLIT;
    const int n = min(cursor[k], CAP);
    const int chunk = (n + SPLIT - 1) / SPLIT;
    const int s0 = min(p * chunk, n);
    const int s1 = min(s0 + chunk, n);

    const int tid  = threadIdx.x;
    const int wave = tid >> 6;
    const int lane = tid & 63;
    const int half = lane >> 5;          // 0 => row A, 1 => row B
    const int l5   = lane & 31;
    const int c0   = l5 << 2;            // this lane's first of 4 columns
    const bool poslane = (l5 == (k >> 2));
    const int  ksub = k & 3;

    const int wlen = (s1 - s0 + 3) >> 2; // per-wave contiguous sub-range
    const int ws0  = s0 + wave * wlen;
    const int ws1  = min(ws0 + wlen, s1);

    const int* bperm = perm + (k << CAPLG);

    float ap0=0,ap1=0,ap2=0,ap3=0;       // sum p
    float sx0=0,sx1=0,sx2=0,sx3=0;       // sum x
    float sl0=0,sl1=0,sl2=0,sl3=0;       // sum log2(1+exp(-x))
    float apos = 0.f;

    for (int tbase = ws0; tbase < ws1; tbase += 64) {
        const int tl = min(64, ws1 - tbase);
        const int pv = (lane < tl) ? bperm[tbase + lane] : 0;  // one load / 64 samples
        const int h  = (tl + 1) >> 1;
        int iA = __shfl(pv, 0);
        int iB = __shfl(pv, (h < tl) ? h : 0);
        float4 cur = *reinterpret_cast<const float4*>(
                         x + (size_t)(half ? iB : iA) * C + c0);
        for (int j = 0; j < h; ++j) {
            float4 nxt = cur;
            if (j + 1 < h) {   // prefetch next pair while computing current
                int nA = __shfl(pv, j + 1);
                int nB = __shfl(pv, (j + 1 + h < tl) ? j + 1 + h : j + 1);
                nxt = *reinterpret_cast<const float4*>(
                          x + (size_t)(half ? nB : nA) * C + c0);
            }
            const bool valid = (half == 0) || (j + h < tl);
            if (valid) {
                float e, u, lu0, lu1, lu2, lu3;
                e = __expf(-cur.x); u = 1.f + e; lu0 = __log2f(u);
                ap0 += fast_rcp(u); sx0 += cur.x; sl0 += lu0;
                e = __expf(-cur.y); u = 1.f + e; lu1 = __log2f(u);
                ap1 += fast_rcp(u); sx1 += cur.y; sl1 += lu1;
                e = __expf(-cur.z); u = 1.f + e; lu2 = __log2f(u);
                ap2 += fast_rcp(u); sx2 += cur.z; sl2 += lu2;
                e = __expf(-cur.w); u = 1.f + e; lu3 = __log2f(u);
                ap3 += fast_rcp(u); sx3 += cur.w; sl3 += lu3;
                if (poslane) {   // target-column log2(1+e) (k uniform -> uniform select)
                    float lsel = (ksub & 2) ? ((ksub & 1) ? lu3 : lu2)
                                            : ((ksub & 1) ? lu1 : lu0);
                    apos += lsel;
                }
            }
            cur = nxt;
        }
    }

    // ---- cross-wave/half LDS reduce (plain float4 writes, no atomics) ----
    __shared__ __align__(16) float sP[8][C];
    __shared__ __align__(16) float sX[8][C];
    __shared__ __align__(16) float sL[8][C];
    __shared__ float sPos[8];
    const int g = (wave << 1) | half;
    *reinterpret_cast<float4*>(&sP[g][c0]) = make_float4(ap0, ap1, ap2, ap3);
    *reinterpret_cast<float4*>(&sX[g][c0]) = make_float4(sx0, sx1, sx2, sx3);
    *reinterpret_cast<float4*>(&sL[g][c0]) = make_float4(sl0, sl1, sl2, sl3);
    if (poslane) sPos[g] = apos;
    __syncthreads();

    float* mine = partial + (size_t)blockIdx.x * PBS;
    if (tid < C) {                        // sum_probs col
        float s = 0.f;
#pragma unroll
        for (int g2 = 0; g2 < 8; ++g2) s += sP[g2][tid];
        mine[tid] = s;
    } else {                              // sum_logneg col: -sum(x) - ln2*sum(log2(1+e))
        const int t = tid - C;
        float sx = 0.f, sl = 0.f;
#pragma unroll
        for (int g2 = 0; g2 < 8; ++g2) { sx += sX[g2][t]; sl += sL[g2][t]; }
        mine[C + t] = -sx - LN2F * sl;
    }
    if (tid == 0) {
        float s = 0.f;
#pragma unroll
        for (int g2 = 0; g2 < 8; ++g2) s += sPos[g2];
        mine[256] = -LN2F * s;            // sum over samples of ln(p_target)
    }
}

// ---------------------------------------------------------------------------
// Fused epilogue (replaces reduce2 + finalize_col + finalize_sum):
// block k gathers COLUMN k of all 2048 partials directly (thread = (class j,
// half p8): 8+8 strided loads, 16-way ILP, L2/L3-hot), reduces pairwise via
// shfl, then wave 0 runs the verified masked-softmax body; round-6/7 ticket
// pattern: last block sums colpart and writes the scalar.
__global__ __launch_bounds__(256)
void fused_finalize(const float* __restrict__ partial, const int* __restrict__ cursor,
                    float* __restrict__ colpart, int* __restrict__ ticket,
                    float* __restrict__ out) {
    const int k   = blockIdx.x;
    const int tid = threadIdx.x;

    __shared__ float spcol[C], slcol[C];
    __shared__ float sposr[SPLIT];

    {   // phase 1: column-k reduction over SPLIT partials per class
        const int j  = tid >> 1;               // class row 0..127
        const int p8 = (tid & 1) * (SPLIT / 2);
        const float* bp = partial + (size_t)(j * SPLIT + p8) * PBS;
        float aP = 0.f, aL = 0.f;
#pragma unroll
        for (int q = 0; q < SPLIT / 2; ++q) {
            aP += bp[q * PBS + k];
            aL += bp[q * PBS + C + k];
        }
        aP += __shfl_xor(aP, 1);               // pair (2j, 2j+1) same wave
        aL += __shfl_xor(aL, 1);
        if ((tid & 1) == 0) { spcol[j] = aP; slcol[j] = aL; }
        if (tid < SPLIT)
            sposr[tid] = partial[(size_t)(k * SPLIT + tid) * PBS + 256];
    }
    __syncthreads();

    // phase 2: wave 0 masked column softmax (lane l: rows l, l+64)
    if (tid < 64) {
        const int l = tid, j0 = l, j1 = l + 64;
        const float c0 = (float)cursor[j0];
        const float c1 = (float)cursor[j1];
        const bool  v0 = (j0 != k) && (c0 > 0.f);
        const bool  v1 = (j1 != k) && (c1 > 0.f);
        const float x0 = v0 ? spcol[j0] / c0 : -INFINITY;
        const float x1 = v1 ? spcol[j1] / c1 : -INFINITY;

        float m = fmaxf(x0, x1);
#pragma unroll
        for (int d = 1; d < 64; d <<= 1) m = fmaxf(m, __shfl_xor(m, d));

        float w0 = v0 ? __expf(x0 - m) : 0.f;
        float w1 = v1 ? __expf(x1 - m) : 0.f;
        float den = w0 + w1;
        float num = (v0 ? w0 * (slcol[j0] / c0) : 0.f)
                  + (v1 ? w1 * (slcol[j1] / c1) : 0.f);
#pragma unroll
        for (int d = 1; d < 64; d <<= 1) { den += __shfl_xor(den, d); num += __shfl_xor(num, d); }

        int last = 0;
        if (l == 0) {
            float colneg = (den > 0.f) ? num / den : 0.f;
            float ck     = (float)cursor[k];
            float ps     = 0.f;
#pragma unroll
            for (int q = 0; q < SPLIT; ++q) ps += sposr[q];
            float pk = (ck > 0.f) ? ps / ck : 0.f;
            colpart[k] = colneg + pk;
            __threadfence();                   // publish colpart before ticket
            last = (atomicAdd(ticket, 1) == C - 1);
        }
        last = __shfl(last, 0);
        if (last) {                            // last block: global sum -> out
            __threadfence();                   // acquire others' colpart
            float s = colpart[l] + colpart[l + 64];
#pragma unroll
            for (int d = 1; d < 64; d <<= 1) s += __shfl_xor(s, d);
            if (l == 0) out[0] = -s;
        }
    }
}

// ---------------------------------------------------------------------------
extern "C" void kernel_launch(void* const* d_in, const int* in_sizes, int n_in,
                              void* d_out, int out_size, void* d_ws, size_t ws_size,
                              hipStream_t stream) {
    const float* x   = (const float*)d_in[0];
    const int*   tgt = (const int*)d_in[1];
    const int B = in_sizes[1];

    int*   cursor  = (int*)d_ws;                          // C ints
    int*   ticket  = cursor + C;                          // 1 int (zeroed with cursor)
    int*   perm    = cursor + C + 16;                     // C*CAP ints
    float* partial = (float*)(perm + C * CAP);            // C*SPLIT*PBS floats
    float* colpart = partial + (size_t)(C * SPLIT) * PBS; // C floats

    hipMemsetAsync(cursor, 0, (C + 16) * sizeof(int), stream);   // cursor + ticket
    scatter_kernel<<<(B + SPB - 1) / SPB, 256, 0, stream>>>(tgt, cursor, perm, B);
    main_kernel<<<C * SPLIT, 256, 0, stream>>>(x, perm, cursor, partial);
    fused_finalize<<<C, 256, 0, stream>>>(partial, cursor, colpart, ticket, (float*)d_out);
}